// Round 11
// baseline (138.859 us; speedup 1.0000x reference)
//
#include <hip/hip_runtime.h>

// Problem constants (from reference)
#define NSTARS 2048
#define BATCH  256
#define PF     28
#define NGE    512
#define GF     32
#define OPD2   65536   // 256*256
#define KTOT   (PF + GF)  // 60
#define TM     16      // batches per block
#define DEPTH  12      // register pipeline depth: 12 x 128cy = 1536cy coverage
#define NGRP   (KTOT / DEPTH)  // 5 groups of 12 k-slices

typedef float f32x4 __attribute__((ext_vector_type(4)));

// ---------------------------------------------------------------------------
// Kernel 1: index search + W = [interm_poly | interm_graph] (k-major layout)
// Wt[k*BATCH + b], k in [0,60)
// ---------------------------------------------------------------------------
__global__ __launch_bounds__(256) void prep_kernel(
    const float* __restrict__ positions,  const float* __restrict__ obs_pos,
    const float* __restrict__ poly_dic,   const float* __restrict__ graph_dic,
    const float* __restrict__ alpha_poly, const float* __restrict__ alpha_graph,
    float* __restrict__ Wt)
{
    const int b = blockIdx.x;   // batch row
    const int t = threadIdx.x;  // 256 threads

    const float p0 = positions[2 * b];
    const float p1 = positions[2 * b + 1];

    // Faithful to argmax(eq.reshape(B,-1))//2 : first star n (row-major over
    // (n, coord)) where EITHER coordinate matches; all-false -> 0.
    int cand = 0x7fffffff;
    #pragma unroll
    for (int i = 0; i < NSTARS / 256; ++i) {
        const int n = t + i * 256;
        const float o0 = obs_pos[2 * n];
        const float o1 = obs_pos[2 * n + 1];
        if (o0 == p0 || o1 == p1) cand = min(cand, n);
    }
    __shared__ int smin[256];
    smin[t] = cand;
    __syncthreads();
    for (int s = 128; s > 0; s >>= 1) {
        if (t < s) smin[t] = min(smin[t], smin[t + s]);
        __syncthreads();
    }
    int idx = smin[0];
    if (idx == 0x7fffffff) idx = 0;  // argmax of all-False returns 0

    // interm_poly[j] = sum_p poly_dic[idx,p] * alpha_poly[p,j]
    if (t < PF) {
        float acc = 0.f;
        #pragma unroll
        for (int p = 0; p < PF; ++p)
            acc += poly_dic[idx * PF + p] * alpha_poly[p * PF + t];
        Wt[t * BATCH + b] = acc;
    }

    // interm_graph[g] = sum_e graph_dic[idx,e] * alpha_graph[e,g]
    // 8 partials of 64 elements each, reduced in LDS.
    __shared__ float psum[8][GF];
    {
        const int g = t & 31;
        const int r = t >> 5;
        float acc = 0.f;
        const int e0 = r * (NGE / 8);
        for (int e = e0; e < e0 + NGE / 8; ++e)
            acc += graph_dic[idx * NGE + e] * alpha_graph[e * GF + g];
        psum[r][g] = acc;
    }
    __syncthreads();
    if (t < GF) {
        float acc = 0.f;
        #pragma unroll
        for (int r = 0; r < 8; ++r) acc += psum[r][t];
        Wt[(PF + t) * BATCH + b] = acc;
    }
}

// ---------------------------------------------------------------------------
// Kernel 2: out[b, ij] = sum_k Wt[k, b] * S[k, ij]
// TM=16 batches x 1024 ij (f32x4/thread) per block, 1024 blocks, XCD swizzle.
//
// R0-R10 ledger (11 variants, all 36-45 us): every structure provided
// latency coverage <= ~512 cyc against a measured effective read latency of
// ~1200-1700 cyc (duty analysis: R1 27%@4w -> period ~1900cy; R6 cov=384 ->
// duty 36% -> raw ~1200; FETCH~8MB => L3/fabric service, not HBM).
// LDS paths are dead ends: per-lane+broadcast ds_read demand exceeds the
// single per-CU LDS pipe before VALU saturates (R4, R10); big scalar W
// thrashes the 16KB K$ (R9).
//
// This kernel: the never-tried axis -- per-wave in-flight depth >= latency.
//   - DEPTH=12 rotating f32x4 register pipeline: every S load has exactly
//     12 x 128cy = 1536cy of issue-to-use distance. No LDS, no barriers,
//     no inline asm; the compiler's own counted vmcnt does the rest.
//   - TM=16: W/block = 3.75 KB (K$-resident scalar path, proven R1) and
//     128cy of FMA issue per k (the coverage multiplier).
//   - ~130 VGPR -> ~12 waves/CU; coverage is per-wave so 3 waves/SIMD
//     suffice when no wave ever stalls.
//   - XCD swizzle keeps the 16 sharers of each S-slice on one XCD
//     (1.92 MB L2-resident working set). Nontemporal stores.
// ---------------------------------------------------------------------------
__global__ __launch_bounds__(256) void main_kernel(
    const float* __restrict__ S_poly, const float* __restrict__ S_graph,
    const float* __restrict__ Wt, float* __restrict__ out)
{
    const int t    = threadIdx.x;
    const int id   = blockIdx.x;            // 0..1023
    const int xcd  = id & 7;
    const int slot = id >> 3;               // 0..127
    const int xb   = xcd * 8 + (slot & 7);  // 0..63 (8 x-slices per XCD)
    const int yb   = slot >> 3;             // 0..15
    const int ij   = xb * 1024 + t * 4;
    const int b0   = yb * TM;

    const float* __restrict__ wp = Wt + b0; // block-uniform -> s_load

    f32x4 acc[TM];
    #pragma unroll
    for (int b = 0; b < TM; ++b) acc[b] = (f32x4)(0.f);

    // This thread's float4 in S slice k (uniform scalar poly/graph select).
    auto srow = [&](int k) -> const f32x4* {
        const float* base = (k < PF) ? (S_poly  + (size_t)k * OPD2)
                                     : (S_graph + (size_t)(k - PF) * OPD2);
        return reinterpret_cast<const f32x4*>(base + ij);
    };

    // one k-step: copy sv, immediately issue reload (k+DEPTH), FMA on copy
    auto kstep = [&](int k, f32x4& sv, bool reload) {
        const f32x4 s = sv;
        if (reload) sv = *srow(k + DEPTH);
        const float* wk = wp + k * BATCH;   // uniform -> s_load
        #pragma unroll
        for (int b = 0; b < TM; ++b)
            acc[b] += wk[b] * s;
    };

    // prologue: fill the 12-deep pipeline
    f32x4 sv0 = *srow(0),  sv1 = *srow(1),  sv2  = *srow(2),  sv3  = *srow(3),
          sv4 = *srow(4),  sv5 = *srow(5),  sv6  = *srow(6),  sv7  = *srow(7),
          sv8 = *srow(8),  sv9 = *srow(9),  sv10 = *srow(10), sv11 = *srow(11);

    #pragma unroll 1
    for (int T = 0; T < NGRP - 1; ++T) {
        const int kg = T * DEPTH;
        kstep(kg + 0,  sv0,  true);
        kstep(kg + 1,  sv1,  true);
        kstep(kg + 2,  sv2,  true);
        kstep(kg + 3,  sv3,  true);
        kstep(kg + 4,  sv4,  true);
        kstep(kg + 5,  sv5,  true);
        kstep(kg + 6,  sv6,  true);
        kstep(kg + 7,  sv7,  true);
        kstep(kg + 8,  sv8,  true);
        kstep(kg + 9,  sv9,  true);
        kstep(kg + 10, sv10, true);
        kstep(kg + 11, sv11, true);
    }
    {   // last group: drain, no reload
        const int kg = (NGRP - 1) * DEPTH;
        kstep(kg + 0,  sv0,  false);
        kstep(kg + 1,  sv1,  false);
        kstep(kg + 2,  sv2,  false);
        kstep(kg + 3,  sv3,  false);
        kstep(kg + 4,  sv4,  false);
        kstep(kg + 5,  sv5,  false);
        kstep(kg + 6,  sv6,  false);
        kstep(kg + 7,  sv7,  false);
        kstep(kg + 8,  sv8,  false);
        kstep(kg + 9,  sv9,  false);
        kstep(kg + 10, sv10, false);
        kstep(kg + 11, sv11, false);
    }

    #pragma unroll
    for (int b = 0; b < TM; ++b) {
        __builtin_nontemporal_store(
            acc[b],
            reinterpret_cast<f32x4*>(out + (size_t)(b0 + b) * OPD2 + ij));
    }
}

// ---------------------------------------------------------------------------
extern "C" void kernel_launch(void* const* d_in, const int* in_sizes, int n_in,
                              void* d_out, int out_size, void* d_ws, size_t ws_size,
                              hipStream_t stream) {
    const float* positions   = (const float*)d_in[0];  // (256, 2)
    const float* obs_pos     = (const float*)d_in[1];  // (2048, 2)
    const float* poly_dic    = (const float*)d_in[2];  // (2048, 28)
    const float* graph_dic   = (const float*)d_in[3];  // (2048, 512)
    const float* alpha_poly  = (const float*)d_in[4];  // (28, 28)
    const float* alpha_graph = (const float*)d_in[5];  // (512, 32)
    const float* S_poly      = (const float*)d_in[6];  // (28, 256, 256)
    const float* S_graph     = (const float*)d_in[7];  // (32, 256, 256)
    float* out = (float*)d_out;                        // (256, 256, 256)

    float* Wt = (float*)d_ws;  // KTOT * BATCH floats = 60 KB

    prep_kernel<<<BATCH, 256, 0, stream>>>(positions, obs_pos, poly_dic,
                                           graph_dic, alpha_poly, alpha_graph,
                                           Wt);

    main_kernel<<<1024, 256, 0, stream>>>(S_poly, S_graph, Wt, out);
}

// Round 12
// 131.885 us; speedup vs baseline: 1.0529x; 1.0529x over previous
//
#include <hip/hip_runtime.h>

// Problem constants (from reference)
#define NSTARS 2048
#define BATCH  256
#define PF     28
#define NGE    512
#define GF     32
#define OPD2   65536   // 256*256
#define KTOT   (PF + GF)  // 60
#define TM     8       // batches per block
#define DEPTH  6       // register pipeline depth (60 % 6 == 0)
#define NGRP   (KTOT / DEPTH)  // 10 groups of 6 k-slices

typedef float f32x4 __attribute__((ext_vector_type(4)));
typedef unsigned int u32;
typedef u32 u32x2 __attribute__((ext_vector_type(2)));

// ---------------------------------------------------------------------------
// Kernel 1: index search + W = [interm_poly | interm_graph] (k-major layout)
// Wt[k*BATCH + b], k in [0,60)
// ---------------------------------------------------------------------------
__global__ __launch_bounds__(256) void prep_kernel(
    const float* __restrict__ positions,  const float* __restrict__ obs_pos,
    const float* __restrict__ poly_dic,   const float* __restrict__ graph_dic,
    const float* __restrict__ alpha_poly, const float* __restrict__ alpha_graph,
    float* __restrict__ Wt)
{
    const int b = blockIdx.x;   // batch row
    const int t = threadIdx.x;  // 256 threads

    const float p0 = positions[2 * b];
    const float p1 = positions[2 * b + 1];

    // Faithful to argmax(eq.reshape(B,-1))//2 : first star n (row-major over
    // (n, coord)) where EITHER coordinate matches; all-false -> 0.
    int cand = 0x7fffffff;
    #pragma unroll
    for (int i = 0; i < NSTARS / 256; ++i) {
        const int n = t + i * 256;
        const float o0 = obs_pos[2 * n];
        const float o1 = obs_pos[2 * n + 1];
        if (o0 == p0 || o1 == p1) cand = min(cand, n);
    }
    __shared__ int smin[256];
    smin[t] = cand;
    __syncthreads();
    for (int s = 128; s > 0; s >>= 1) {
        if (t < s) smin[t] = min(smin[t], smin[t + s]);
        __syncthreads();
    }
    int idx = smin[0];
    if (idx == 0x7fffffff) idx = 0;  // argmax of all-False returns 0

    // interm_poly[j] = sum_p poly_dic[idx,p] * alpha_poly[p,j]
    if (t < PF) {
        float acc = 0.f;
        #pragma unroll
        for (int p = 0; p < PF; ++p)
            acc += poly_dic[idx * PF + p] * alpha_poly[p * PF + t];
        Wt[t * BATCH + b] = acc;
    }

    // interm_graph[g] = sum_e graph_dic[idx,e] * alpha_graph[e,g]
    // 8 partials of 64 elements each, reduced in LDS.
    __shared__ float psum[8][GF];
    {
        const int g = t & 31;
        const int r = t >> 5;
        float acc = 0.f;
        const int e0 = r * (NGE / 8);
        for (int e = e0; e < e0 + NGE / 8; ++e)
            acc += graph_dic[idx * NGE + e] * alpha_graph[e * GF + g];
        psum[r][g] = acc;
    }
    __syncthreads();
    if (t < GF) {
        float acc = 0.f;
        #pragma unroll
        for (int r = 0; r < 8; ++r) acc += psum[r][t];
        Wt[(PF + t) * BATCH + b] = acc;
    }
}

// ---------------------------------------------------------------------------
// Kernel 1b: convert S (fp32) -> Sb (bf16, round-to-nearest-even), k-major
// [60][65536] ushort. 23.6 MB of HBM traffic, ~4-5 us.
// ---------------------------------------------------------------------------
__global__ __launch_bounds__(256) void conv_kernel(
    const float* __restrict__ S_poly, const float* __restrict__ S_graph,
    u32* __restrict__ Sb)   // packed pairs: 60*65536/2 u32
{
    // 8 elems per thread: 60*65536/8 = 491520 threads = 1920 blocks
    const int e0 = (blockIdx.x * 256 + threadIdx.x) * 8;
    const int k  = e0 >> 16;            // 65536 elems per k-row, 8 | 65536
    const int ij = e0 & 65535;
    const float* src = (k < PF) ? (S_poly  + (size_t)k * OPD2 + ij)
                                : (S_graph + (size_t)(k - PF) * OPD2 + ij);
    u32 packed[4];
    #pragma unroll
    for (int p = 0; p < 4; ++p) {
        u32 lo = __float_as_uint(src[2 * p]);
        u32 hi = __float_as_uint(src[2 * p + 1]);
        lo = (lo + 0x7FFFu + ((lo >> 16) & 1u)) >> 16;   // RNE to bf16
        hi = (hi + 0x7FFFu + ((hi >> 16) & 1u)) & 0xFFFF0000u;
        packed[p] = lo | hi;
    }
    // 16 B coalesced store of 8 bf16
    *reinterpret_cast<f32x4*>(Sb + (e0 >> 1)) = *reinterpret_cast<f32x4*>(packed);
}

// ---------------------------------------------------------------------------
// Kernel 2: out[b, ij] = sum_k Wt[k, b] * S[k, ij]   (S in bf16)
// TM=8 batches x 1024 ij per block (4 ij/thread), 2048 blocks, XCD swizzle.
//
// R11's VGPR=72 proved the compiler collapses every source-level load
// pipeline (sinks reloads to their use). 12 scheduling variants all hit a
// ~35-45 us wall. This round changes the AXIS: same geometry as R6 (best
// total, 124.2 us), but S pre-converted to bf16 -> 8 B instead of 16 B per
// k-load. Same request count (clean A/B on BYTES): 503 -> 251 MB cache
// reads, per-XCD working set 1.9 MB -> 983 KB (comfortably L2-resident).
// Unpack = 1 shift + 1 and per bf16 pair (operands consumed as f32 bits).
//  - W on the scalar path (2 KB/block, K$-resident).
//  - 24 KB dead-LDS throttle: 6 blocks/CU resident of 8/CU work -> ragged
//    generations overlap the 66 MB store tail (R6's winning trick).
//  - Nontemporal stores.
// ---------------------------------------------------------------------------
__global__ __launch_bounds__(256) void main_kernel(
    const u32* __restrict__ Sb, const float* __restrict__ Wt,
    float* __restrict__ out)
{
    __shared__ float lds_throttle[6144];  // 24 KB -> 6 blocks/CU

    const int t    = threadIdx.x;
    const int id   = blockIdx.x;            // 0..2047
    const int xcd  = id & 7;
    const int slot = id >> 3;               // 0..255
    const int xb   = xcd * 8 + (slot & 7);  // 0..63 (8 x-slices per XCD)
    const int yb   = slot >> 3;             // 0..31
    const int ij   = xb * 1024 + t * 4;
    const int b0   = yb * TM;

    // Opaque never-true guard keeps the LDS allocation live without traffic.
    if (id == -1) lds_throttle[t] = Wt[t];

    const float* __restrict__ wp = Wt + b0; // block-uniform -> s_load

    f32x4 acc[TM];
    #pragma unroll
    for (int b = 0; b < TM; ++b) acc[b] = (f32x4)(0.f);

    // This thread's 4 bf16 (one u32x2) in S slice k.
    auto srow = [&](int k) -> const u32x2* {
        return reinterpret_cast<const u32x2*>(Sb + (((size_t)k << 16) + ij >> 1));
    };

    // one k-step: unpack sv, issue reload (k+DEPTH), FMA
    auto kstep = [&](int k, u32x2& sv, bool reload) {
        const u32 p0 = sv.x, p1 = sv.y;
        if (reload) sv = *srow(k + DEPTH);
        f32x4 s;
        s.x = __uint_as_float(p0 << 16);
        s.y = __uint_as_float(p0 & 0xFFFF0000u);
        s.z = __uint_as_float(p1 << 16);
        s.w = __uint_as_float(p1 & 0xFFFF0000u);
        const float* wk = wp + k * BATCH;   // uniform -> s_load
        #pragma unroll
        for (int b = 0; b < TM; ++b)
            acc[b] += wk[b] * s;
    };

    // prologue: fill the 6-deep pipeline
    u32x2 sv0 = *srow(0), sv1 = *srow(1), sv2 = *srow(2),
          sv3 = *srow(3), sv4 = *srow(4), sv5 = *srow(5);

    #pragma unroll 1
    for (int T = 0; T < NGRP - 1; ++T) {
        const int kg = T * DEPTH;
        kstep(kg + 0, sv0, true);
        kstep(kg + 1, sv1, true);
        kstep(kg + 2, sv2, true);
        kstep(kg + 3, sv3, true);
        kstep(kg + 4, sv4, true);
        kstep(kg + 5, sv5, true);
    }
    {   // last group: drain
        const int kg = (NGRP - 1) * DEPTH;
        kstep(kg + 0, sv0, false);
        kstep(kg + 1, sv1, false);
        kstep(kg + 2, sv2, false);
        kstep(kg + 3, sv3, false);
        kstep(kg + 4, sv4, false);
        kstep(kg + 5, sv5, false);
    }

    #pragma unroll
    for (int b = 0; b < TM; ++b) {
        __builtin_nontemporal_store(
            acc[b],
            reinterpret_cast<f32x4*>(out + (size_t)(b0 + b) * OPD2 + ij));
    }
}

// ---------------------------------------------------------------------------
extern "C" void kernel_launch(void* const* d_in, const int* in_sizes, int n_in,
                              void* d_out, int out_size, void* d_ws, size_t ws_size,
                              hipStream_t stream) {
    const float* positions   = (const float*)d_in[0];  // (256, 2)
    const float* obs_pos     = (const float*)d_in[1];  // (2048, 2)
    const float* poly_dic    = (const float*)d_in[2];  // (2048, 28)
    const float* graph_dic   = (const float*)d_in[3];  // (2048, 512)
    const float* alpha_poly  = (const float*)d_in[4];  // (28, 28)
    const float* alpha_graph = (const float*)d_in[5];  // (512, 32)
    const float* S_poly      = (const float*)d_in[6];  // (28, 256, 256)
    const float* S_graph     = (const float*)d_in[7];  // (32, 256, 256)
    float* out = (float*)d_out;                        // (256, 256, 256)

    float* Wt = (float*)d_ws;                          // 60*256*4 = 61440 B
    u32*   Sb = (u32*)((char*)d_ws + 65536);           // 60*65536*2 = 7.86 MB

    prep_kernel<<<BATCH, 256, 0, stream>>>(positions, obs_pos, poly_dic,
                                           graph_dic, alpha_poly, alpha_graph,
                                           Wt);
    conv_kernel<<<1920, 256, 0, stream>>>(S_poly, S_graph, Sb);

    main_kernel<<<2048, 256, 0, stream>>>(Sb, Wt, (float*)d_out);
}

// Round 14
// 123.350 us; speedup vs baseline: 1.1257x; 1.0692x over previous
//
#include <hip/hip_runtime.h>

// Problem constants (from reference)
#define NSTARS 2048
#define BATCH  256
#define PF     28
#define NGE    512
#define GF     32
#define OPD2   65536   // 256*256
#define KTOT   (PF + GF)  // 60
#define NTILE  4096    // 65536/16 ij-tiles

// workspace layout
#define WA_OFF 61440                     // Wt: 60*256*4 = 61440 B
#define WA_HALF 32768                    // one A-frag stream: 16*2*64*16 B
#define SB_OFF (WA_OFF + 2 * WA_HALF)    // Wa_hi + Wa_lo = 64 KB
#define SB_BYTES ((size_t)NTILE * 2 * 64 * 16)   // 8,388,608
#define WS_NEED (SB_OFF + SB_BYTES)              // 8,515,584

typedef float f32x4 __attribute__((ext_vector_type(4)));
typedef short bf16x8 __attribute__((ext_vector_type(8)));
typedef unsigned int u32;

// ---------------------------------------------------------------------------
// Kernel 1: index search + W = [interm_poly | interm_graph] (k-major layout)
// Wt[k*BATCH + b], k in [0,60)
// ---------------------------------------------------------------------------
__global__ __launch_bounds__(256) void prep_kernel(
    const float* __restrict__ positions,  const float* __restrict__ obs_pos,
    const float* __restrict__ poly_dic,   const float* __restrict__ graph_dic,
    const float* __restrict__ alpha_poly, const float* __restrict__ alpha_graph,
    float* __restrict__ Wt)
{
    const int b = blockIdx.x;   // batch row
    const int t = threadIdx.x;  // 256 threads

    const float p0 = positions[2 * b];
    const float p1 = positions[2 * b + 1];

    // Faithful to argmax(eq.reshape(B,-1))//2 : first star n (row-major over
    // (n, coord)) where EITHER coordinate matches; all-false -> 0.
    int cand = 0x7fffffff;
    #pragma unroll
    for (int i = 0; i < NSTARS / 256; ++i) {
        const int n = t + i * 256;
        const float o0 = obs_pos[2 * n];
        const float o1 = obs_pos[2 * n + 1];
        if (o0 == p0 || o1 == p1) cand = min(cand, n);
    }
    __shared__ int smin[256];
    smin[t] = cand;
    __syncthreads();
    for (int s = 128; s > 0; s >>= 1) {
        if (t < s) smin[t] = min(smin[t], smin[t + s]);
        __syncthreads();
    }
    int idx = smin[0];
    if (idx == 0x7fffffff) idx = 0;  // argmax of all-False returns 0

    // interm_poly[j] = sum_p poly_dic[idx,p] * alpha_poly[p,j]
    if (t < PF) {
        float acc = 0.f;
        #pragma unroll
        for (int p = 0; p < PF; ++p)
            acc += poly_dic[idx * PF + p] * alpha_poly[p * PF + t];
        Wt[t * BATCH + b] = acc;
    }

    // interm_graph[g] = sum_e graph_dic[idx,e] * alpha_graph[e,g]
    __shared__ float psum[8][GF];
    {
        const int g = t & 31;
        const int r = t >> 5;
        float acc = 0.f;
        const int e0 = r * (NGE / 8);
        for (int e = e0; e < e0 + NGE / 8; ++e)
            acc += graph_dic[idx * NGE + e] * alpha_graph[e * GF + g];
        psum[r][g] = acc;
    }
    __syncthreads();
    if (t < GF) {
        float acc = 0.f;
        #pragma unroll
        for (int r = 0; r < 8; ++r) acc += psum[r][t];
        Wt[(PF + t) * BATCH + b] = acc;
    }
}

// ---------------------------------------------------------------------------
// bf16 RNE helpers
// ---------------------------------------------------------------------------
__device__ __forceinline__ u32 bf16_rne(u32 x) {       // fp32 bits -> bf16 (low 16)
    return (x + 0x7FFFu + ((x >> 16) & 1u)) >> 16;
}
__device__ __forceinline__ float bf16_to_f32(u32 h) {  // bf16 (low 16) -> fp32
    return __uint_as_float(h << 16);
}

// ---------------------------------------------------------------------------
// Kernel 1b: W (fp32, k-major) -> TWO bf16 A-fragment streams:
//   Wa_hi = bf16(W),  Wa_lo = bf16(W - float(Wa_hi))   (error ~2^-18 rel)
// A-frag (16x16x32 bf16): lane l holds 8 bf16; m = l&15, k = 32*kf+(l>>4)*8+e.
// Stream index: ((mtile*2+kf)*64 + lane)*16B; k >= 60 zero-padded (exact).
// ---------------------------------------------------------------------------
__global__ __launch_bounds__(256) void prep2_kernel(
    const float* __restrict__ Wt, u32* __restrict__ Wa_hi, u32* __restrict__ Wa_lo)
{
    const int f     = blockIdx.x * 256 + threadIdx.x;  // 0..2047
    const int lane  = f & 63;
    const int kf    = (f >> 6) & 1;
    const int mtile = f >> 7;                          // 0..15
    const int m     = mtile * 16 + (lane & 15);
    const int kbase = kf * 32 + (lane >> 4) * 8;
    u32 hi_pk[4], lo_pk[4];
    #pragma unroll
    for (int p = 0; p < 4; ++p) {
        u32 h[2], l[2];
        #pragma unroll
        for (int q = 0; q < 2; ++q) {
            const int k = kbase + 2 * p + q;
            float w = (k < KTOT) ? Wt[k * BATCH + m] : 0.f;
            const u32 hb = bf16_rne(__float_as_uint(w));
            const float resid = w - bf16_to_f32(hb);
            h[q] = hb;
            l[q] = bf16_rne(__float_as_uint(resid));
        }
        hi_pk[p] = h[0] | (h[1] << 16);
        lo_pk[p] = l[0] | (l[1] << 16);
    }
    *reinterpret_cast<f32x4*>(Wa_hi + f * 4) = *reinterpret_cast<f32x4*>(hi_pk);
    *reinterpret_cast<f32x4*>(Wa_lo + f * 4) = *reinterpret_cast<f32x4*>(lo_pk);
}

// ---------------------------------------------------------------------------
// Kernel 1c: S (fp32, k-major) -> Sb bf16 B-fragment stream.
// B-frag: lane l holds 8 bf16; n(ij) = l&15, k = 32*kf + (l>>4)*8+e.
// Sb[((tile*2+kf)*64 + lane)*16B]; tile = ij>>4; k >= 60 zero-padded.
// (bf16-S under the abs threshold is PROVEN by R12's pass.)
// ---------------------------------------------------------------------------
__global__ __launch_bounds__(256) void conv_kernel(
    const float* __restrict__ S_poly, const float* __restrict__ S_graph,
    u32* __restrict__ Sb)
{
    const int f    = blockIdx.x * 256 + threadIdx.x;   // 0..524287
    const int lane = f & 63;
    const int kf   = (f >> 6) & 1;
    const int tile = f >> 7;                           // 0..4095
    const int ij   = tile * 16 + (lane & 15);
    const int kbase = kf * 32 + (lane >> 4) * 8;
    u32 pk[4];
    #pragma unroll
    for (int p = 0; p < 4; ++p) {
        u32 b16[2];
        #pragma unroll
        for (int q = 0; q < 2; ++q) {
            const int k = kbase + 2 * p + q;
            u32 v = 0u;
            if (k < KTOT) {
                const float s = (k < PF) ? S_poly[(size_t)k * OPD2 + ij]
                                         : S_graph[(size_t)(k - PF) * OPD2 + ij];
                v = bf16_rne(__float_as_uint(s));
            }
            b16[q] = v;
        }
        pk[p] = b16[0] | (b16[1] << 16);
    }
    *reinterpret_cast<f32x4*>(Sb + (size_t)f * 4) = *reinterpret_cast<f32x4*>(pk);
}

// ---------------------------------------------------------------------------
// Kernel 2 (MFMA): out[b][ij] = sum_k W[k][b] * S[k][ij]  as 16x16x32 bf16,
// with W = W_hi + W_lo double-bf16 (4 MFMA per 16x16 output tile).
// Block = 64 batches x 256 ij; grid 1024 (256 x-chunks x 4 y), XCD-swizzled
// (per-XCD S stream 1 MB, L2-resident). Wave w owns 4 ij-tiles x 4 M-tiles:
// 16 A-frag loads held in regs; per ij-tile {2 B-frag loads, 16 MFMA,
// 64 nt dword stores}. Zero LDS, zero barriers, linear coalesced loads.
// Latency-critical load count ~6x lower than R6's VALU path; floor =
// compulsory 256 KB/CU store stream.
// D layout (m89-verified): col = lane&15, row = (lane>>4)*4 + reg.
// ---------------------------------------------------------------------------
__global__ __launch_bounds__(256) void mfma_kernel(
    const u32* __restrict__ Sb, const u32* __restrict__ Wa_hi,
    const u32* __restrict__ Wa_lo, float* __restrict__ out)
{
    const int t    = threadIdx.x;
    const int id   = blockIdx.x;            // 0..1023
    const int xcd  = id & 7;
    const int slot = id >> 3;               // 0..127
    const int xb   = xcd * 32 + (slot & 31);// 0..255 (32 x-chunks per XCD)
    const int yb   = slot >> 5;             // 0..3
    const int w    = t >> 6;                // wave 0..3
    const int lane = t & 63;
    const int b0   = yb * 64;
    const int Tb   = xb * 16 + w * 4;       // first ij-tile of this wave

    // A-frags for this block's 4 M-tiles x 2 k-frags x {hi,lo} (16 x 16B)
    bf16x8 Ah[4][2], Al[4][2];
    #pragma unroll
    for (int mt = 0; mt < 4; ++mt)
        #pragma unroll
        for (int kf = 0; kf < 2; ++kf) {
            const int fi = (((yb * 4 + mt) * 2 + kf) * 64 + lane) * 4;
            Ah[mt][kf] = *reinterpret_cast<const bf16x8*>(Wa_hi + fi);
            Al[mt][kf] = *reinterpret_cast<const bf16x8*>(Wa_lo + fi);
        }

    const int row = (lane >> 4) * 4;   // D row base (batch)
    const int col = lane & 15;         // D col (ij)

    #pragma unroll
    for (int tt = 0; tt < 4; ++tt) {
        const int T = Tb + tt;
        const bf16x8 B0 = *reinterpret_cast<const bf16x8*>(
            Sb + ((size_t)(T * 2 + 0) * 64 + lane) * 4);
        const bf16x8 B1 = *reinterpret_cast<const bf16x8*>(
            Sb + ((size_t)(T * 2 + 1) * 64 + lane) * 4);
        #pragma unroll
        for (int mt = 0; mt < 4; ++mt) {
            f32x4 acc = (f32x4)(0.f);
            acc = __builtin_amdgcn_mfma_f32_16x16x32_bf16(Al[mt][0], B0, acc, 0, 0, 0);
            acc = __builtin_amdgcn_mfma_f32_16x16x32_bf16(Al[mt][1], B1, acc, 0, 0, 0);
            acc = __builtin_amdgcn_mfma_f32_16x16x32_bf16(Ah[mt][0], B0, acc, 0, 0, 0);
            acc = __builtin_amdgcn_mfma_f32_16x16x32_bf16(Ah[mt][1], B1, acc, 0, 0, 0);
            float* op = out + (size_t)(b0 + mt * 16 + row) * OPD2 + T * 16 + col;
            #pragma unroll
            for (int j = 0; j < 4; ++j)
                __builtin_nontemporal_store(acc[j], op + (size_t)j * OPD2);
        }
    }
}

// ---------------------------------------------------------------------------
// Fallback (fp32, proven-correct R1-style) if workspace can't hold Sb.
// ---------------------------------------------------------------------------
__global__ __launch_bounds__(256) void fb_kernel(
    const float* __restrict__ S_poly, const float* __restrict__ S_graph,
    const float* __restrict__ Wt, float* __restrict__ out)
{
    const int t  = threadIdx.x;
    const int ij = blockIdx.x * 1024 + t * 4;
    const int b0 = blockIdx.y * 16;
    f32x4 acc[16];
    #pragma unroll
    for (int b = 0; b < 16; ++b) acc[b] = (f32x4)(0.f);
    const float* __restrict__ wp = Wt + b0;
    #pragma unroll 2
    for (int k = 0; k < PF; ++k) {
        const f32x4 s = *reinterpret_cast<const f32x4*>(S_poly + (size_t)k * OPD2 + ij);
        #pragma unroll
        for (int b = 0; b < 16; ++b) acc[b] += wp[k * BATCH + b] * s;
    }
    #pragma unroll 2
    for (int k = 0; k < GF; ++k) {
        const f32x4 s = *reinterpret_cast<const f32x4*>(S_graph + (size_t)k * OPD2 + ij);
        #pragma unroll
        for (int b = 0; b < 16; ++b) acc[b] += wp[(PF + k) * BATCH + b] * s;
    }
    #pragma unroll
    for (int b = 0; b < 16; ++b)
        *reinterpret_cast<f32x4*>(out + (size_t)(b0 + b) * OPD2 + ij) = acc[b];
}

// ---------------------------------------------------------------------------
extern "C" void kernel_launch(void* const* d_in, const int* in_sizes, int n_in,
                              void* d_out, int out_size, void* d_ws, size_t ws_size,
                              hipStream_t stream) {
    const float* positions   = (const float*)d_in[0];  // (256, 2)
    const float* obs_pos     = (const float*)d_in[1];  // (2048, 2)
    const float* poly_dic    = (const float*)d_in[2];  // (2048, 28)
    const float* graph_dic   = (const float*)d_in[3];  // (2048, 512)
    const float* alpha_poly  = (const float*)d_in[4];  // (28, 28)
    const float* alpha_graph = (const float*)d_in[5];  // (512, 32)
    const float* S_poly      = (const float*)d_in[6];  // (28, 256, 256)
    const float* S_graph     = (const float*)d_in[7];  // (32, 256, 256)
    float* out = (float*)d_out;                        // (256, 256, 256)

    float* Wt = (float*)d_ws;

    prep_kernel<<<BATCH, 256, 0, stream>>>(positions, obs_pos, poly_dic,
                                           graph_dic, alpha_poly, alpha_graph,
                                           Wt);

    if (ws_size >= WS_NEED) {
        u32* Wa_hi = (u32*)((char*)d_ws + WA_OFF);
        u32* Wa_lo = (u32*)((char*)d_ws + WA_OFF + WA_HALF);
        u32* Sb    = (u32*)((char*)d_ws + SB_OFF);
        prep2_kernel<<<8, 256, 0, stream>>>(Wt, Wa_hi, Wa_lo);
        conv_kernel<<<2048, 256, 0, stream>>>(S_poly, S_graph, Sb);
        mfma_kernel<<<1024, 256, 0, stream>>>(Sb, Wa_hi, Wa_lo, out);
    } else {
        dim3 grid(OPD2 / 1024, BATCH / 16);
        fb_kernel<<<grid, 256, 0, stream>>>(S_poly, S_graph, Wt, out);
    }
}